// Round 5
// baseline (41.486 us; speedup 1.0000x reference)
//
#include <hip/hip_runtime.h>
#include <math.h>

// FrequencyAdaptiveNorm: multi-scale (w=5,10,20) centered sliding-window
// normalization over L, softmax-weighted fusion.
// x: (B=32, L=2048, F=256) f32, weights: (3,) f32, out: same shape.
//
// v5: v4 + grouped software prefetch. The 32-element chunk is processed in
// 4 groups of 8; group g+1's loads are issued into a ping-pong register
// buffer before group g is consumed, keeping 8 loads in flight (v4 kept ~2,
// exposing L2/L3 latency -> VALUBusy stuck at 58%). All buffer indices are
// compile-time constants after full unroll (no scratch; v3 lesson).

#define B_ 32
#define L_ 2048
#define F_ 256
#define TL 32   // L-chunk per block; grid = (64, 32) = 2048 blocks
#define G_ 8    // prefetch group size

__device__ __forceinline__ float fin(float v) {
    return isfinite(v) ? v : 0.0f;   // nan_to_num(nan=0, +inf=0, -inf=0)
}

// ---------------- interior: no bounds checks, deep prefetch ----------------
__device__ __forceinline__ void run_interior(const float* __restrict__ xb,
                                             float* __restrict__ ob,
                                             const int l0,
                                             const float ws5, const float ws10,
                                             const float ws20) {
    const float eps = 1e-5f;

    // delay line: ring[d] = x[l0-10+d], d = 0..20
    float ring[21];
#pragma unroll
    for (int d = 0; d < 21; ++d) ring[d] = fin(xb[(l0 - 10 + d) * F_]);

    // running sums at j=l0: w5=ring[8..12], w10=ring[5..14], w20=ring[0..19]
    float s5 = 0.f, q5 = 0.f, s10 = 0.f, q10 = 0.f, s20 = 0.f, q20 = 0.f;
#pragma unroll
    for (int d = 0; d < 20; ++d) { s20 += ring[d]; q20 = fmaf(ring[d], ring[d], q20); }
#pragma unroll
    for (int d = 5; d < 15; ++d) { s10 += ring[d]; q10 = fmaf(ring[d], ring[d], q10); }
#pragma unroll
    for (int d = 8; d < 13; ++d) { s5  += ring[d]; q5  = fmaf(ring[d], ring[d], q5);  }

    // prefetch ping-pong buffers (all indices static after unroll)
    float pfA[G_], pfB[G_];
#pragma unroll
    for (int i = 0; i < G_; ++i) pfA[i] = fin(xb[(l0 + 11 + i) * F_]);

#pragma unroll
    for (int g = 0; g < TL / G_; ++g) {
        // issue next group's loads into the other buffer
        if (g + 1 < TL / G_) {
            if ((g & 1) == 0) {
#pragma unroll
                for (int i = 0; i < G_; ++i)
                    pfB[i] = fin(xb[(l0 + 11 + (g + 1) * G_ + i) * F_]);
            } else {
#pragma unroll
                for (int i = 0; i < G_; ++i)
                    pfA[i] = fin(xb[(l0 + 11 + (g + 1) * G_ + i) * F_]);
            }
        }

        // consume current group
#pragma unroll
        for (int i = 0; i < G_; ++i) {
            const int t = g * G_ + i;
            const int j = l0 + t;
            const float vnew = ((g & 1) == 0) ? pfA[i] : pfB[i];

            const float xc = ring[10];
            float acc;
            {   // w=5
                const float mean  = s5 * 0.2f;
                const float mean2 = q5 * 0.2f;
                const float var   = fmaxf(fmaf(-mean, mean, mean2), 0.0f);
                acc = ws5 * ((xc - mean) * rsqrtf(var + eps));
            }
            {   // w=10
                const float mean  = s10 * 0.1f;
                const float mean2 = q10 * 0.1f;
                const float var   = fmaxf(fmaf(-mean, mean, mean2), 0.0f);
                acc = fmaf(ws10, (xc - mean) * rsqrtf(var + eps), acc);
            }
            {   // w=20
                const float mean  = s20 * 0.05f;
                const float mean2 = q20 * 0.05f;
                const float var   = fmaxf(fmaf(-mean, mean, mean2), 0.0f);
                acc = fmaf(ws20, (xc - mean) * rsqrtf(var + eps), acc);
            }
            ob[j * F_] = acc;

            // slide windows j -> j+1:  s += a-r;  q += (a-r)(a+r)
            {
                const float a = ring[13], r = ring[8];
                const float d = a - r, p = a + r;
                s5 += d; q5 = fmaf(d, p, q5);
            }
            {
                const float a = ring[15], r = ring[5];
                const float d = a - r, p = a + r;
                s10 += d; q10 = fmaf(d, p, q10);
            }
            {
                const float a = ring[20], r = ring[0];
                const float d = a - r, p = a + r;
                s20 += d; q20 = fmaf(d, p, q20);
            }

            // shift delay line — fully unrolled => pure SSA renaming
#pragma unroll
            for (int d = 0; d < 20; ++d) ring[d] = ring[d + 1];
            ring[20] = vnew;
        }
    }
}

// ---------------- edge: checked path (2 of 64 chunks) ----------------
__device__ __forceinline__ void run_edge(const float* __restrict__ xb,
                                         float* __restrict__ ob,
                                         const int l0,
                                         const float ws5, const float ws10,
                                         const float ws20) {
    const float eps = 1e-5f;

    float ring[21];
#pragma unroll
    for (int d = 0; d < 21; ++d) {
        const int l = l0 - 10 + d;
        ring[d] = ((unsigned)l < (unsigned)L_) ? fin(xb[l * F_]) : 0.0f;
    }

    float s5 = 0.f, q5 = 0.f, s10 = 0.f, q10 = 0.f, s20 = 0.f, q20 = 0.f;
#pragma unroll
    for (int d = 0; d < 20; ++d) { s20 += ring[d]; q20 = fmaf(ring[d], ring[d], q20); }
#pragma unroll
    for (int d = 5; d < 15; ++d) { s10 += ring[d]; q10 = fmaf(ring[d], ring[d], q10); }
#pragma unroll
    for (int d = 8; d < 13; ++d) { s5  += ring[d]; q5  = fmaf(ring[d], ring[d], q5);  }

#pragma unroll
    for (int t = 0; t < TL; ++t) {
        const int j = l0 + t;
        const int ln = j + 11;
        const float vnew = ((unsigned)ln < (unsigned)L_) ? fin(xb[ln * F_]) : 0.0f;

        const float xc = ring[10];
        float acc = 0.0f;
        if (j >= 2 && j <= L_ - 3) {
            const float mean  = s5 * 0.2f;
            const float mean2 = q5 * 0.2f;
            const float var   = fmaxf(fmaf(-mean, mean, mean2), 0.0f);
            acc = fmaf(ws5, (xc - mean) * rsqrtf(var + eps), acc);
        }
        if (j >= 5 && j <= L_ - 5) {
            const float mean  = s10 * 0.1f;
            const float mean2 = q10 * 0.1f;
            const float var   = fmaxf(fmaf(-mean, mean, mean2), 0.0f);
            acc = fmaf(ws10, (xc - mean) * rsqrtf(var + eps), acc);
        }
        if (j >= 10 && j <= L_ - 10) {
            const float mean  = s20 * 0.05f;
            const float mean2 = q20 * 0.05f;
            const float var   = fmaxf(fmaf(-mean, mean, mean2), 0.0f);
            acc = fmaf(ws20, (xc - mean) * rsqrtf(var + eps), acc);
        }
        ob[j * F_] = acc;

        { const float a = ring[13], r = ring[8];  const float d = a - r, p = a + r; s5  += d; q5  = fmaf(d, p, q5);  }
        { const float a = ring[15], r = ring[5];  const float d = a - r, p = a + r; s10 += d; q10 = fmaf(d, p, q10); }
        { const float a = ring[20], r = ring[0];  const float d = a - r, p = a + r; s20 += d; q20 = fmaf(d, p, q20); }

#pragma unroll
        for (int d = 0; d < 20; ++d) ring[d] = ring[d + 1];
        ring[20] = vnew;
    }
}

__global__ __launch_bounds__(256, 8)
void fan_kernel(const float* __restrict__ x,
                const float* __restrict__ w,
                float* __restrict__ out) {
    const int f  = threadIdx.x;           // 0..255 == F
    const int b  = blockIdx.y;
    const int l0 = blockIdx.x * TL;
    const float* xb = x   + (size_t)b * L_ * F_ + f;
    float*       ob = out + (size_t)b * L_ * F_ + f;

    // softmax over the 3 fusion logits (uniform across threads)
    const float w0 = w[0], w1 = w[1], w2 = w[2];
    const float m  = fmaxf(w0, fmaxf(w1, w2));
    const float e0 = expf(w0 - m), e1 = expf(w1 - m), e2 = expf(w2 - m);
    const float inv = 1.0f / (e0 + e1 + e2);
    const float ws5 = e0 * inv, ws10 = e1 * inv, ws20 = e2 * inv;

    if (blockIdx.x != 0 && blockIdx.x != gridDim.x - 1)
        run_interior(xb, ob, l0, ws5, ws10, ws20);
    else
        run_edge(xb, ob, l0, ws5, ws10, ws20);
}

extern "C" void kernel_launch(void* const* d_in, const int* in_sizes, int n_in,
                              void* d_out, int out_size, void* d_ws, size_t ws_size,
                              hipStream_t stream) {
    const float* x = (const float*)d_in[0];
    const float* w = (const float*)d_in[1];
    float* out = (float*)d_out;
    (void)in_sizes; (void)n_in; (void)out_size; (void)d_ws; (void)ws_size;

    dim3 grid(L_ / TL, B_);   // (64, 32) = 2048 blocks
    dim3 block(F_);           // 256 threads, one per feature column
    hipLaunchKernelGGL(fan_kernel, grid, block, 0, stream, x, w, out);
}